// Round 12
// baseline (142.132 us; speedup 1.0000x reference)
//
#include <hip/hip_runtime.h>
#include <math.h>
#include <stdint.h>

#define NV 50000      // visible nodes
#define NH 5000       // hidden nodes
#define NN 55000      // total nodes
#define NCB 313       // coarse buckets: k>>4, 16 k's each (313*16 = 5008 >= 5000)
#define BCAP 4096     // region capacity per bucket (mean ~3195, +16 sigma)
#define KSLOT 384     // per-k staging cap (mean 200, +13 sigma)
#define CHUNK 4096    // coarse-pass edges per block

// ws layout:
//   bits       : 0       , NV*4 u32   = 800000 B (128-bit spin mask per visible)
//   coarse_cnt : 800000  , NCB u32    = 1252 B
//   recs       : 801280  , NCB*BCAP*8 = 10.26 MB (uint2 {v | (k&15)<<16, w_bits})

// sign-select mask: 0xFFFFFFFF if bit bsh of word set, else 0
__device__ __forceinline__ uint32_t selmask(uint32_t word, uint32_t bsh) {
    return (uint32_t)((int32_t)(word << (31u - bsh)) >> 31);
}

// Pass 0: bit-pack s; block 0 zeros coarse_cnt (replaces hipMemsetAsync).
__global__ void __launch_bounds__(256) pack_zero_kernel(
        const int* __restrict__ s, uint32_t* __restrict__ bits,
        uint32_t* __restrict__ coarse_cnt) {
    if (blockIdx.x == 0)
        for (int i = threadIdx.x; i < NCB; i += 256) coarse_cnt[i] = 0u;
    int tid = blockIdx.x * 256 + threadIdx.x;
    int v = tid >> 2;
    int g = tid & 3;
    if (v >= NV) return;
    const int* col = s + (size_t)g * 32 * NN + v;
    uint32_t w = 0;
#pragma unroll
    for (int j = 0; j < 32; ++j)
        w |= (uint32_t)(col[(size_t)j * NN] & 1) << j;
    bits[(size_t)v * 4 + g] = w;   // consecutive tid -> consecutive addresses
}

// Pass A: coarse split (unchanged since R10 — proven). Counting-sort each
// 4096-edge chunk by bucket (k>>4) in LDS, reserve contiguous global runs,
// drain staged records LINEARLY -> coalesced HBM writes (avg run 13 recs).
__global__ void __launch_bounds__(256) coarse_split_kernel(
        const int4* __restrict__ seg4, const int4* __restrict__ adj4,
        const float4* __restrict__ quad4,
        uint32_t* __restrict__ coarse_cnt, uint2* __restrict__ recs, int E) {
    __shared__ uint32_t hist[320];       // per-bucket counts (padded to scan width)
    __shared__ uint32_t loc[320];        // inclusive prefix
    __shared__ uint32_t cur[NCB];        // staging cursor
    __shared__ uint32_t gbase[NCB];      // reserved global run base
    __shared__ __align__(16) uint2 st[CHUNK];   // 32 KB staging
    __shared__ uint32_t dst[CHUNK];             // absolute dest, ~0u = dropped
    const int tid = threadIdx.x;
    for (int i = tid; i < 320; i += 256) hist[i] = 0u;
    __syncthreads();

    const int c0 = blockIdx.x * CHUNK;
    const int nloc = min(CHUNK, E - c0);         // E, c0 multiples of 4
    int kreg[16];
#pragma unroll
    for (int j = 0; j < 4; ++j) {
        int t4 = (c0 >> 2) + j * 256 + tid;
        bool ok = t4 < ((c0 + nloc) >> 2);
        int4 sg = ok ? seg4[t4] : make_int4(-1, -1, -1, -1);
        kreg[j * 4 + 0] = sg.x; kreg[j * 4 + 1] = sg.y;
        kreg[j * 4 + 2] = sg.z; kreg[j * 4 + 3] = sg.w;
        if (ok) {
            atomicAdd(&hist[sg.x >> 4], 1u);
            atomicAdd(&hist[sg.y >> 4], 1u);
            atomicAdd(&hist[sg.z >> 4], 1u);
            atomicAdd(&hist[sg.w >> 4], 1u);
        }
    }
    __syncthreads();
    for (int i = tid; i < NCB; i += 256)
        gbase[i] = atomicAdd(&coarse_cnt[i], hist[i]);
    for (int i = tid; i < 320; i += 256) loc[i] = hist[i];
    __syncthreads();
    for (int d = 1; d < 320; d <<= 1) {          // Hillis-Steele scan
        uint32_t v0 = 0, v1 = 0;
        int i1 = tid + 256;
        if (tid >= d) v0 = loc[tid - d];
        if (i1 < 320 && i1 >= d) v1 = loc[i1 - d];
        __syncthreads();
        if (tid >= d) loc[tid] += v0;
        if (i1 < 320 && i1 >= d) loc[i1] += v1;
        __syncthreads();
    }
    for (int i = tid; i < NCB; i += 256) cur[i] = loc[i] - hist[i];  // exclusive
    __syncthreads();
#pragma unroll
    for (int j = 0; j < 4; ++j) {
        int t4 = (c0 >> 2) + j * 256 + tid;
        if (t4 < ((c0 + nloc) >> 2)) {
            int4 a = adj4[t4];
            float4 q = quad4[t4];   // flat_j_idx == arange(E)
#pragma unroll
            for (int cmp = 0; cmp < 4; ++cmp) {
                int k = kreg[j * 4 + cmp];
                int v = (cmp == 0) ? a.x : (cmp == 1) ? a.y : (cmp == 2) ? a.z : a.w;
                float w = (cmp == 0) ? q.x : (cmp == 1) ? q.y : (cmp == 2) ? q.z : q.w;
                int bk = k >> 4;
                uint32_t slot = atomicAdd(&cur[bk], 1u);
                uint32_t rank = gbase[bk] + (slot - (loc[bk] - hist[bk]));
                st[slot] = make_uint2((uint32_t)v | ((uint32_t)(k & 15) << 16),
                                      __float_as_uint(w));
                dst[slot] = (rank < BCAP) ? (uint32_t)bk * BCAP + rank : ~0u;
            }
        }
    }
    __syncthreads();
    for (int i = tid; i < nloc; i += 256) {
        uint32_t d = dst[i];
        if (d != ~0u) recs[d] = st[i];
    }
}

// Pass B: quarter-bucket field v2 — 3 phases, 3 barriers (R11 had 5 phases).
// Block = 4 k's. Phase 1: single vectorized region scan writes matching
// records DIRECTLY into word-major LDS rows (bits4 gather inline; position
// via 4-counter LDS atomic; sum_w in registers -> shuffle+LDS-atomic).
// Phase 2: accumulate acc = sum(w & selmask) for all 4 lists via broadcast
// ds_read_b128 (1 instr per record per 128 batches — LDS-issue floor).
// Phase 3: eff = 2*acc - sum_w + linear, one float4 out-write per b.
// Swizzle puts a bucket's 4 quarters on one XCD (full 64B out-line assembly).
__global__ void __launch_bounds__(256) quarter_field_kernel(
        const uint32_t* __restrict__ coarse_cnt, const uint2* __restrict__ recs,
        const uint4* __restrict__ bits4, const float* __restrict__ linear,
        float* __restrict__ out) {
    const int x = blockIdx.x;
    const int j = (x & 7) * 157 + (x >> 3);   // XCD-contiguous quarter index
    const int bkt = j >> 2;
    const int q = j & 3;
    if (bkt >= NCB) return;                   // 4 idle blocks (j 1252..1255)
    const int tid = threadIdx.x;

    __shared__ uint32_t cur4[4];
    __shared__ float swp[4];                              // per-list sum_w
    __shared__ __align__(16) uint32_t rows[4][5][KSLOT];  // 30.7 KB
    __shared__ float part[4][256];                        // 4 KB

    if (tid < 4) cur4[tid] = 0u;
    else if (tid < 8) swp[tid - 4] = 0.f;
    __syncthreads();

    // phase 1: scan bucket region (2 records per uint4 load), direct staging
    int cnt = (int)min(coarse_cnt[bkt], (uint32_t)BCAP);
    const uint4* region4 = (const uint4*)(recs + (size_t)bkt * BCAP);
    float sw0 = 0.f, sw1 = 0.f, sw2 = 0.f, sw3 = 0.f;
    for (int i2 = tid; i2 * 2 < cnt; i2 += 256) {
        uint4 rr = region4[i2];
#pragma unroll
        for (int h = 0; h < 2; ++h) {
            int idx = i2 * 2 + h;
            if (idx >= cnt) break;
            uint32_t rx = h ? rr.z : rr.x;
            uint32_t ry = h ? rr.w : rr.y;
            int kl = (int)((rx >> 16) & 15u);
            if ((kl >> 2) == q) {
                int l = kl & 3;
                uint32_t p = atomicAdd(&cur4[l], 1u);
                if (p < KSLOT) {
                    uint4 mw = bits4[rx & 0xFFFFu];
                    rows[l][0][p] = mw.x;
                    rows[l][1][p] = mw.y;
                    rows[l][2][p] = mw.z;
                    rows[l][3][p] = mw.w;
                    rows[l][4][p] = ry;
                    float wv = __uint_as_float(ry);
                    if (l == 0) sw0 += wv;
                    else if (l == 1) sw1 += wv;
                    else if (l == 2) sw2 += wv;
                    else sw3 += wv;
                }
            }
        }
    }
    // reduce sum_w: wave shuffle, then one LDS atomic per wave per list
#pragma unroll
    for (int off = 32; off; off >>= 1) {
        sw0 += __shfl_down(sw0, off);
        sw1 += __shfl_down(sw1, off);
        sw2 += __shfl_down(sw2, off);
        sw3 += __shfl_down(sw3, off);
    }
    if ((tid & 63) == 0) {
        atomicAdd(&swp[0], sw0);
        atomicAdd(&swp[1], sw1);
        atomicAdd(&swp[2], sw2);
        atomicAdd(&swp[3], sw3);
    }
    __syncthreads();

    // pad each list's w-row to a multiple of 8 (word rows may stay garbage)
    if (tid < 4) {
        int c = min((int)cur4[tid], KSLOT);
        int T8 = (c + 7) & ~7;
        for (int t = c; t < T8; ++t) rows[tid][4][t] = 0u;
        cur4[tid] = (uint32_t)T8;
    }
    __syncthreads();

    // phase 2: accumulate — 256 threads = 128 batches x 2 record-halves
    const int b = tid & 127;
    const int grp = tid >> 7;
    const uint32_t bsh = (uint32_t)(b & 31);
    const int widx = b >> 5;
#pragma unroll
    for (int kk = 0; kk < 4; ++kk) {
        int T8 = (int)cur4[kk];
        const uint32_t* mrow = rows[kk][widx];
        const uint32_t* wrow = rows[kk][4];
        float a0 = 0.f, a1 = 0.f, a2 = 0.f, a3 = 0.f;
        for (int i = grp * 4; i < T8; i += 8) {
            uint4 mm = *(const uint4*)(mrow + i);   // broadcast ds_read_b128
            uint4 ww = *(const uint4*)(wrow + i);
            a0 += __uint_as_float(ww.x & selmask(mm.x, bsh));
            a1 += __uint_as_float(ww.y & selmask(mm.y, bsh));
            a2 += __uint_as_float(ww.z & selmask(mm.z, bsh));
            a3 += __uint_as_float(ww.w & selmask(mm.w, bsh));
        }
        part[kk][tid] = (a0 + a1) + (a2 + a3);
    }
    __syncthreads();

    // phase 3: output — float4 of 4 adjacent k's per batch
    if (tid < 128) {
        int k0 = bkt * 16 + q * 4;
        if (k0 + 3 < NH) {            // bkt 312, q>=2 entirely out of range
            float4 o;
            float* op = (float*)&o;
#pragma unroll
            for (int kk = 0; kk < 4; ++kk) {
                float acc = part[kk][tid] + part[kk][tid + 128];
                float e = 2.f * acc - swp[kk] + linear[NV + k0 + kk];
                op[kk] = tanhf(-e);
            }
            *(float4*)(out + (size_t)tid * NH + k0) = o;  // k0 mult of 4 -> aligned
        }
    }
}

extern "C" void kernel_launch(void* const* d_in, const int* in_sizes, int n_in,
                              void* d_out, int out_size, void* d_ws, size_t ws_size,
                              hipStream_t stream) {
    const float* linear = (const float*)d_in[0];
    const float* quad   = (const float*)d_in[1];
    const int*   s      = (const int*)d_in[2];
    const int*   adj    = (const int*)d_in[3];
    const int*   seg    = (const int*)d_in[5];
    const int E = in_sizes[5];
    float* out = (float*)d_out;

    char* ws = (char*)d_ws;
    uint32_t* bits       = (uint32_t*)(ws);
    uint32_t* coarse_cnt = (uint32_t*)(ws + 800000);
    uint2*    recs       = (uint2*)   (ws + 801280);

    pack_zero_kernel<<<(NV * 4 + 255) / 256, 256, 0, stream>>>(s, bits, coarse_cnt);
    const int nchunk = (E + CHUNK - 1) / CHUNK;       // 245
    coarse_split_kernel<<<nchunk, 256, 0, stream>>>(
        (const int4*)seg, (const int4*)adj, (const float4*)quad, coarse_cnt, recs, E);
    quarter_field_kernel<<<1256, 256, 0, stream>>>(coarse_cnt, recs, (const uint4*)bits,
                                                   linear, out);
}

// Round 13
// 139.645 us; speedup vs baseline: 1.0178x; 1.0178x over previous
//
#include <hip/hip_runtime.h>
#include <math.h>
#include <stdint.h>

#define NV 50000      // visible nodes
#define NH 5000       // hidden nodes
#define NN 55000      // total nodes
#define NCB 313       // coarse buckets: k>>4, 16 k's each (313*16 = 5008 >= 5000)
#define BCAP 4096     // region capacity per bucket (mean ~3195, +16 sigma)
#define KSLOT 384     // per-k staging cap (mean 200, +13 sigma; multiple of 16)
#define KPAD 388      // padded row length: 388 mod 32 = 4 -> widx rows on distinct bank quads
#define CHUNK 4096    // coarse-pass edges per block

// ws layout:
//   bits       : 0       , NV*4 u32   = 800000 B (128-bit spin mask per visible)
//   coarse_cnt : 800000  , NCB u32    = 1252 B
//   recs       : 801280  , NCB*BCAP*8 = 10.26 MB (uint2 {v | (k&15)<<16, w_bits})

// Pass 0: bit-pack s; block 0 zeros coarse_cnt (replaces hipMemsetAsync).
__global__ void __launch_bounds__(256) pack_zero_kernel(
        const int* __restrict__ s, uint32_t* __restrict__ bits,
        uint32_t* __restrict__ coarse_cnt) {
    if (blockIdx.x == 0)
        for (int i = threadIdx.x; i < NCB; i += 256) coarse_cnt[i] = 0u;
    int tid = blockIdx.x * 256 + threadIdx.x;
    int v = tid >> 2;
    int g = tid & 3;
    if (v >= NV) return;
    const int* col = s + (size_t)g * 32 * NN + v;
    uint32_t w = 0;
#pragma unroll
    for (int j = 0; j < 32; ++j)
        w |= (uint32_t)(col[(size_t)j * NN] & 1) << j;
    bits[(size_t)v * 4 + g] = w;   // consecutive tid -> consecutive addresses
}

// Pass A: coarse split (unchanged since R10 — proven). Counting-sort each
// 4096-edge chunk by bucket (k>>4) in LDS, reserve contiguous global runs,
// drain staged records LINEARLY -> coalesced HBM writes (avg run 13 recs).
__global__ void __launch_bounds__(256) coarse_split_kernel(
        const int4* __restrict__ seg4, const int4* __restrict__ adj4,
        const float4* __restrict__ quad4,
        uint32_t* __restrict__ coarse_cnt, uint2* __restrict__ recs, int E) {
    __shared__ uint32_t hist[320];       // per-bucket counts (padded to scan width)
    __shared__ uint32_t loc[320];        // inclusive prefix
    __shared__ uint32_t cur[NCB];        // staging cursor
    __shared__ uint32_t gbase[NCB];      // reserved global run base
    __shared__ __align__(16) uint2 st[CHUNK];   // 32 KB staging
    __shared__ uint32_t dst[CHUNK];             // absolute dest, ~0u = dropped
    const int tid = threadIdx.x;
    for (int i = tid; i < 320; i += 256) hist[i] = 0u;
    __syncthreads();

    const int c0 = blockIdx.x * CHUNK;
    const int nloc = min(CHUNK, E - c0);         // E, c0 multiples of 4
    int kreg[16];
#pragma unroll
    for (int j = 0; j < 4; ++j) {
        int t4 = (c0 >> 2) + j * 256 + tid;
        bool ok = t4 < ((c0 + nloc) >> 2);
        int4 sg = ok ? seg4[t4] : make_int4(-1, -1, -1, -1);
        kreg[j * 4 + 0] = sg.x; kreg[j * 4 + 1] = sg.y;
        kreg[j * 4 + 2] = sg.z; kreg[j * 4 + 3] = sg.w;
        if (ok) {
            atomicAdd(&hist[sg.x >> 4], 1u);
            atomicAdd(&hist[sg.y >> 4], 1u);
            atomicAdd(&hist[sg.z >> 4], 1u);
            atomicAdd(&hist[sg.w >> 4], 1u);
        }
    }
    __syncthreads();
    for (int i = tid; i < NCB; i += 256)
        gbase[i] = atomicAdd(&coarse_cnt[i], hist[i]);
    for (int i = tid; i < 320; i += 256) loc[i] = hist[i];
    __syncthreads();
    for (int d = 1; d < 320; d <<= 1) {          // Hillis-Steele scan
        uint32_t v0 = 0, v1 = 0;
        int i1 = tid + 256;
        if (tid >= d) v0 = loc[tid - d];
        if (i1 < 320 && i1 >= d) v1 = loc[i1 - d];
        __syncthreads();
        if (tid >= d) loc[tid] += v0;
        if (i1 < 320 && i1 >= d) loc[i1] += v1;
        __syncthreads();
    }
    for (int i = tid; i < NCB; i += 256) cur[i] = loc[i] - hist[i];  // exclusive
    __syncthreads();
#pragma unroll
    for (int j = 0; j < 4; ++j) {
        int t4 = (c0 >> 2) + j * 256 + tid;
        if (t4 < ((c0 + nloc) >> 2)) {
            int4 a = adj4[t4];
            float4 q = quad4[t4];   // flat_j_idx == arange(E)
#pragma unroll
            for (int cmp = 0; cmp < 4; ++cmp) {
                int k = kreg[j * 4 + cmp];
                int v = (cmp == 0) ? a.x : (cmp == 1) ? a.y : (cmp == 2) ? a.z : a.w;
                float w = (cmp == 0) ? q.x : (cmp == 1) ? q.y : (cmp == 2) ? q.z : q.w;
                int bk = k >> 4;
                uint32_t slot = atomicAdd(&cur[bk], 1u);
                uint32_t rank = gbase[bk] + (slot - (loc[bk] - hist[bk]));
                st[slot] = make_uint2((uint32_t)v | ((uint32_t)(k & 15) << 16),
                                      __float_as_uint(w));
                dst[slot] = (rank < BCAP) ? (uint32_t)bk * BCAP + rank : ~0u;
            }
        }
    }
    __syncthreads();
    for (int i = tid; i < nloc; i += 256) {
        uint32_t d = dst[i];
        if (d != ~0u) recs[d] = st[i];
    }
}

// Pass B: quarter-bucket field v3. Block = 4 k's. Phases:
//  1. scan: vectorized region read, filter kl>>2==q into compact st4 (LDS)
//     — compaction BEFORE gather so the bits4 gathers are full-lane-active
//     (R12's inline gather under 25%-divergence regressed: lesson learned).
//  2. stage: wave w owns list w: full-active uint4 bits4 gathers, word-major
//     rows (padded KPAD=388 so widx rows sit on distinct bank quads).
//  3. accumulate: each thread owns TWO bits of one word (batches b, b+16):
//     one mm/ww ds_read_b128 pair feeds 8 accumulations — HALVES the LDS
//     instruction count vs R11 (the measured floor). Sign via XOR trick:
//     acc += w ^ ((~word << (31-bsh)) & 0x80000000) -> no sum_w pass at all.
//  4. out: float4 of 4 adjacent k's per batch; bucket's quarters on one XCD.
__global__ void __launch_bounds__(256) quarter_field_kernel(
        const uint32_t* __restrict__ coarse_cnt, const uint2* __restrict__ recs,
        const uint4* __restrict__ bits4, const float* __restrict__ linear,
        float* __restrict__ out) {
    const int x = blockIdx.x;
    const int j = (x & 7) * 157 + (x >> 3);   // XCD-contiguous quarter index
    const int bkt = j >> 2;
    const int q = j & 3;
    if (bkt >= NCB) return;                   // 4 idle blocks (j 1252..1255)
    const int tid = threadIdx.x;

    __shared__ uint32_t cur4[4];
    __shared__ __align__(16) uint2 st4[4][KSLOT];          // 12.3 KB
    __shared__ __align__(16) uint32_t rows[4][5][KPAD];    // 31.0 KB
    __shared__ float part[4][256][2];                      // 8 KB

    if (tid < 4) cur4[tid] = 0u;
    __syncthreads();

    // phase 1: scan bucket region (2 records per uint4 load) -> compact st4
    int cnt = (int)min(coarse_cnt[bkt], (uint32_t)BCAP);
    const uint4* region4 = (const uint4*)(recs + (size_t)bkt * BCAP);
    for (int i2 = tid; i2 * 2 < cnt; i2 += 256) {
        uint4 rr = region4[i2];
#pragma unroll
        for (int h = 0; h < 2; ++h) {
            int idx = i2 * 2 + h;
            if (idx >= cnt) break;
            uint32_t rx = h ? rr.z : rr.x;
            uint32_t ry = h ? rr.w : rr.y;
            int kl = (int)((rx >> 16) & 15u);
            if ((kl >> 2) == q) {
                int l = kl & 3;
                uint32_t p = atomicAdd(&cur4[l], 1u);
                if (p < KSLOT) st4[l][p] = make_uint2(rx, ry);
            }
        }
    }
    __syncthreads();

    // phase 2: wave w stages list w (full-lane-active gathers), pads, and
    // publishes rounded count. No extra barrier: wave-private work.
    {
        const int w = tid >> 6;
        const int lane = tid & 63;
        int c = min((int)cur4[w], KSLOT);
        int T16 = (c + 15) & ~15;
        for (int t = c + lane; t < T16; t += 64) rows[w][4][t] = 0u;  // w=0 pad
        for (int t = lane; t < c; t += 64) {
            uint2 r = st4[w][t];
            uint4 mw = bits4[r.x & 0xFFFFu];
            rows[w][0][t] = mw.x;
            rows[w][1][t] = mw.y;
            rows[w][2][t] = mw.z;
            rows[w][3][t] = mw.w;
            rows[w][4][t] = r.y;
        }
        if (lane == 0) cur4[w] = (uint32_t)T16;
    }
    __syncthreads();

    // phase 3: accumulate. 256 threads = 4 record-quarter waves x 64 (widx,bl)
    // pairs; thread covers batches b0 = widx*32+bl and b1 = b0+16.
    const int grp  = tid >> 6;          // wave = record quarter (wave-uniform i)
    const int pair = tid & 63;
    const int bl   = pair & 15;
    const int widx = pair >> 4;
    const uint32_t sh0 = (uint32_t)(31 - bl);   // bit bl      -> sign bit
    const uint32_t sh1 = (uint32_t)(15 - bl);   // bit bl + 16 -> sign bit
#pragma unroll
    for (int kk = 0; kk < 4; ++kk) {
        int T16 = (int)cur4[kk];
        const uint32_t* mrow = &rows[kk][widx][0];
        const uint32_t* wrow = &rows[kk][4][0];
        float a0 = 0.f, b0 = 0.f, a1 = 0.f, b1 = 0.f;
        for (int i = grp * 4; i < T16; i += 16) {
            uint4 mm = *(const uint4*)(mrow + i);   // 4 distinct bank-quads, 16-lane bcast
            uint4 ww = *(const uint4*)(wrow + i);   // wave-uniform broadcast
            uint32_t n0 = ~mm.x, n1 = ~mm.y, n2 = ~mm.z, n3 = ~mm.w;
            a0 += __uint_as_float(ww.x ^ ((n0 << sh0) & 0x80000000u));
            a1 += __uint_as_float(ww.x ^ ((n0 << sh1) & 0x80000000u));
            b0 += __uint_as_float(ww.y ^ ((n1 << sh0) & 0x80000000u));
            b1 += __uint_as_float(ww.y ^ ((n1 << sh1) & 0x80000000u));
            a0 += __uint_as_float(ww.z ^ ((n2 << sh0) & 0x80000000u));
            a1 += __uint_as_float(ww.z ^ ((n2 << sh1) & 0x80000000u));
            b0 += __uint_as_float(ww.w ^ ((n3 << sh0) & 0x80000000u));
            b1 += __uint_as_float(ww.w ^ ((n3 << sh1) & 0x80000000u));
        }
        part[kk][tid][0] = a0 + b0;   // batch b0 partial (this record quarter)
        part[kk][tid][1] = a1 + b1;   // batch b1 partial
    }
    __syncthreads();

    // phase 4: output — float4 of 4 adjacent k's per batch
    if (tid < 128) {
        int b = tid;
        int bl31 = b & 31;
        int p = (b >> 5) * 16 + (bl31 & 15);   // pair index within wave
        int slot = bl31 >> 4;                  // which of the thread's 2 bits
        int k0 = bkt * 16 + q * 4;
        if (k0 + 3 < NH) {                     // bkt 312, q>=2 out of range
            float4 o;
            float* op = (float*)&o;
#pragma unroll
            for (int kk = 0; kk < 4; ++kk) {
                float acc = part[kk][p][slot] + part[kk][64 + p][slot]
                          + part[kk][128 + p][slot] + part[kk][192 + p][slot];
                float e = acc + linear[NV + k0 + kk];
                op[kk] = tanhf(-e);
            }
            *(float4*)(out + (size_t)b * NH + k0) = o;  // k0 mult of 4 -> aligned
        }
    }
}

extern "C" void kernel_launch(void* const* d_in, const int* in_sizes, int n_in,
                              void* d_out, int out_size, void* d_ws, size_t ws_size,
                              hipStream_t stream) {
    const float* linear = (const float*)d_in[0];
    const float* quad   = (const float*)d_in[1];
    const int*   s      = (const int*)d_in[2];
    const int*   adj    = (const int*)d_in[3];
    const int*   seg    = (const int*)d_in[5];
    const int E = in_sizes[5];
    float* out = (float*)d_out;

    char* ws = (char*)d_ws;
    uint32_t* bits       = (uint32_t*)(ws);
    uint32_t* coarse_cnt = (uint32_t*)(ws + 800000);
    uint2*    recs       = (uint2*)   (ws + 801280);

    pack_zero_kernel<<<(NV * 4 + 255) / 256, 256, 0, stream>>>(s, bits, coarse_cnt);
    const int nchunk = (E + CHUNK - 1) / CHUNK;       // 245
    coarse_split_kernel<<<nchunk, 256, 0, stream>>>(
        (const int4*)seg, (const int4*)adj, (const float4*)quad, coarse_cnt, recs, E);
    quarter_field_kernel<<<1256, 256, 0, stream>>>(coarse_cnt, recs, (const uint4*)bits,
                                                   linear, out);
}